// Round 1
// baseline (685.409 us; speedup 1.0000x reference)
//
#include <hip/hip_runtime.h>
#include <hip/hip_bf16.h>
#include <cstdint>

// AttentionGNNLayer, R9: receiver-range bucketing + LDS f32 aggregation.
//   per-node A=h@W1a+b1, B=h@W1b, q=h@Wq+bq, k=h@Wk+bk  (bf16-packed Ak/Bq as in R8)
//   edges counting-scattered into 782 buckets of 128 receiver-nodes each;
//   one block per bucket accumulates relu(A[r]+B[s]+c*w)*sigmoid(q.k) into LDS f32,
//   writes relu(agg) directly to out (f32 accumulation; no global atomics, no relu pass).
// Why: R8 counters showed WRITE_SIZE=165.7MB == surviving-edges*64B -- device-scope
// pk-bf16 atomics write through the fabric (per-XCD L2 can't absorb them). LDS agg
// removes that traffic entirely and makes the Ak[r] gather L1-resident (16KB slice).
// Dot reduce via DPP (quad_perm/row_mirror) instead of ds_swizzle: LDS pipe now does agg.
// Fallback to the proven R8 atomic path if workspace is too small.

#define EPG 8          // edges per 16-lane subgroup
#define NBMAX 1024     // max buckets (128 nodes each -> n_nodes <= 131072)
#define BSHIFT 7
#define BSIZE (1 << BSHIFT)
#define SC_CHUNK 12288 // edges per scatter block (1024 thr * 12)
#define HIST_BLOCKS 512

typedef int   vint4   __attribute__((ext_vector_type(4)));
typedef float vfloat4 __attribute__((ext_vector_type(4)));

__device__ __forceinline__ float bf16lo(uint32_t u) {
    uint32_t b = (u & 0xFFFFu) << 16;
    float f; __builtin_memcpy(&f, &b, 4); return f;
}
__device__ __forceinline__ float bf16hi(uint32_t u) {
    uint32_t b = u & 0xFFFF0000u;
    float f; __builtin_memcpy(&f, &b, 4); return f;
}
__device__ __forceinline__ uint32_t pack_bf16(float lo, float hi) {
    __hip_bfloat16 l = __float2bfloat16(lo);
    __hip_bfloat16 h = __float2bfloat16(hi);
    uint16_t lb, hb;
    __builtin_memcpy(&lb, &l, 2);
    __builtin_memcpy(&hb, &h, 2);
    return (uint32_t)lb | ((uint32_t)hb << 16);
}
__device__ __forceinline__ void atomic_pk_add_bf16(uint32_t* addr, uint32_t val) {
    asm volatile("global_atomic_pk_add_bf16 %0, %1, off" :: "v"(addr), "v"(val) : "memory");
}

// VALU-pipe cross-lane add within 16-lane rows (replaces ds_swizzle shuffles).
// xor1 = quad_perm[1,0,3,2]=0xB1, xor2 = quad_perm[2,3,0,1]=0x4E,
// "xor4" = row_half_mirror 0x141, "xor8" = row_mirror 0x140 (mirrors are valid
// partners for a sum-reduce).
template<int CTRL>
__device__ __forceinline__ float dpp_addstep(float x) {
    int y = __builtin_amdgcn_update_dpp(0, __builtin_bit_cast(int, x), CTRL, 0xF, 0xF, true);
    return x + __builtin_bit_cast(float, y);
}

// ---- node precompute: one wave per node (wave-uniform h row -> scalar/broadcast
// loads, no shuffles). lanes 0..31: (A,k)->Ak, lanes 32..63: (B,q)->Bq.
// Also: receiver histogram (bucketed mode, blocks < HIST_BLOCKS) and agg zero (fallback).

__global__ __launch_bounds__(256) void node_precompute(
    const float* __restrict__ h, const float* __restrict__ W1,
    const float* __restrict__ b1, const float* __restrict__ Wq,
    const float* __restrict__ bq, const float* __restrict__ Wk,
    const float* __restrict__ bk,
    uint32_t* __restrict__ Ak, uint32_t* __restrict__ Bq,
    uint4* __restrict__ aggz, int n_aggz,
    const int* __restrict__ receivers, int n_edges,
    int* __restrict__ ghist, int nb,
    int n_nodes)
{
    __shared__ float sW[4][32 * 33];   // +1 pad: conflict-free column reads
    __shared__ int lh[NBMAX];
    int tid = threadIdx.x;

    if (nb > 0) for (int b = tid; b < nb; b += 256) lh[b] = 0;
    for (int i = tid; i < 1024; i += 256) {
        int j = i >> 5, t = i & 31;
        sW[0][j * 33 + t] = W1[i];          // W1a (receiver part)
        sW[1][j * 33 + t] = W1[1024 + i];   // W1b (sender part)
        sW[2][j * 33 + t] = Wq[i];
        sW[3][j * 33 + t] = Wk[i];
    }
    __syncthreads();

    int lane = tid & 63;
    int t    = lane & 31;         // channel
    int half = lane >> 5;         // 0: (A,k), 1: (B,q)
    int wave = tid >> 6;          // 0..3

    int ma = half ? 1 : 0;        // W1b : W1a
    int mb = half ? 2 : 3;        // Wq  : Wk
    float wa[32], wb[32];
    #pragma unroll
    for (int j = 0; j < 32; ++j) {
        wa[j] = sW[ma][j * 33 + t];
        wb[j] = sW[mb][j * 33 + t];
    }
    float ba = half ? 0.f   : b1[t];
    float bb = half ? bq[t] : bk[t];
    uint32_t* dst = half ? Bq : Ak;

    // receiver histogram -> global bucket counts (bucketed mode only)
    if (nb > 0 && blockIdx.x < HIST_BLOCKS) {
        for (int e = blockIdx.x * 256 + tid; e < n_edges; e += HIST_BLOCKS * 256)
            atomicAdd(&lh[receivers[e] >> BSHIFT], 1);
        __syncthreads();
        for (int b = tid; b < nb; b += 256) {
            int c = lh[b];
            if (c) atomicAdd(&ghist[b], c);
        }
    }

    // zero bf16 accumulator (fallback mode only; n_aggz==0 otherwise)
    for (int i = blockIdx.x * 256 + tid; i < n_aggz; i += gridDim.x * 256)
        aggz[i] = make_uint4(0u, 0u, 0u, 0u);

    for (int n0 = blockIdx.x * 4 + wave; n0 < n_nodes; n0 += gridDim.x * 4) {
        int n = __builtin_amdgcn_readfirstlane(n0);   // wave-uniform -> s_load-able
        const float* hr = h + (size_t)n * 32;
        float aa = ba, ab = bb;
        #pragma unroll
        for (int j = 0; j < 32; ++j) {
            float hj = hr[j];
            aa = fmaf(hj, wa[j], aa);
            ab = fmaf(hj, wb[j], ab);
        }
        dst[(size_t)n * 32 + t] = pack_bf16(aa, ab);
    }
}

// ---- exclusive scan of 8-aligned bucket regions (one block) ----

__global__ __launch_bounds__(1024) void scan_kernel(
    const int* __restrict__ counts, int* __restrict__ bases,
    int* __restrict__ cursor, int nb)
{
    __shared__ int s[1024];
    int tid = threadIdx.x;
    int v = (tid < nb) ? ((counts[tid] + 7) & ~7) : 0;   // align regions to 8 edges
    s[tid] = v;
    __syncthreads();
    for (int off = 1; off < 1024; off <<= 1) {
        int t = (tid >= off) ? s[tid - off] : 0;
        __syncthreads();
        s[tid] += t;
        __syncthreads();
    }
    if (tid < nb) {
        int base = s[tid] - v;    // exclusive
        bases[tid]  = base;
        cursor[tid] = base;
    }
}

// ---- counting scatter: exact block-level ranks, coalesced per-bucket clusters ----

__global__ __launch_bounds__(1024) void scatter_kernel(
    const int* __restrict__ senders, const int* __restrict__ receivers,
    const float* __restrict__ couplings,
    int* __restrict__ cursor,
    int* __restrict__ rb, int* __restrict__ sb, float* __restrict__ cb,
    int n_edges, int e_half, int nb)
{
    __shared__ int h[NBMAX];
    __shared__ int gb[NBMAX];
    int tid = threadIdx.x;
    long e0 = (long)blockIdx.x * SC_CHUNK;

    for (int b = tid; b < nb; b += 1024) h[b] = 0;
    __syncthreads();
    for (int i = tid; i < SC_CHUNK; i += 1024) {          // phase A: count
        long e = e0 + i;
        if (e < n_edges) atomicAdd(&h[receivers[e] >> BSHIFT], 1);
    }
    __syncthreads();
    for (int b = tid; b < nb; b += 1024) {                // phase B: reserve
        int c = h[b];
        gb[b] = c ? atomicAdd(&cursor[b], c) : 0;
        h[b] = 0;
    }
    __syncthreads();
    for (int i = tid; i < SC_CHUNK; i += 1024) {          // phase C: rank + write
        long e = e0 + i;
        if (e < n_edges) {
            int   r = receivers[e];
            int   s = senders[e];
            float c = couplings[e < (long)e_half ? e : e - e_half];
            int   b = r >> BSHIFT;
            int pos = gb[b] + atomicAdd(&h[b], 1);
            rb[pos] = r; sb[pos] = s; cb[pos] = c;
        }
    }
}

// ---- bucketed edge kernel: one block = one 128-node receiver slice, LDS f32 agg ----

__global__ __launch_bounds__(256) void edge_bucket_kernel(
    const uint32_t* __restrict__ Ak, const uint32_t* __restrict__ Bq,
    const int* __restrict__ rb, const int* __restrict__ sb,
    const float* __restrict__ cb,
    const int* __restrict__ bases, const int* __restrict__ counts,
    const float* __restrict__ W1,
    float* __restrict__ out, int n_nodes)
{
    __shared__ float sagg[BSIZE * 33];   // +1-dword pad: row spreads across banks
    int tid  = threadIdx.x;
    int lane = tid & 15;
    int b    = blockIdx.x;
    int nb0  = b << BSHIFT;
    int ncnt = min(BSIZE, n_nodes - nb0);

    for (int i = tid; i < BSIZE * 33; i += 256) sagg[i] = 0.f;

    float w0 = W1[64 * 32 + 2 * lane];   // coupling row (L1-resident)
    float w1 = W1[64 * 32 + 2 * lane + 1];
    int cnt  = counts[b];
    int base = bases[b];                 // multiple of 8 -> vint4-aligned
    __syncthreads();

    for (int e0 = (tid >> 4) * EPG; e0 < cnt; e0 += 16 * EPG) {
        int r[EPG], s[EPG]; float c[EPG];
        if (e0 + EPG <= cnt) {
            #pragma unroll
            for (int v = 0; v < EPG / 4; ++v) {
                vint4   rv = __builtin_nontemporal_load((const vint4*)(rb + base + e0) + v);
                vint4   sv = __builtin_nontemporal_load((const vint4*)(sb + base + e0) + v);
                vfloat4 cv = __builtin_nontemporal_load((const vfloat4*)(cb + base + e0) + v);
                r[4*v+0]=rv.x; r[4*v+1]=rv.y; r[4*v+2]=rv.z; r[4*v+3]=rv.w;
                s[4*v+0]=sv.x; s[4*v+1]=sv.y; s[4*v+2]=sv.z; s[4*v+3]=sv.w;
                c[4*v+0]=cv.x; c[4*v+1]=cv.y; c[4*v+2]=cv.z; c[4*v+3]=cv.w;
            }
        } else {
            #pragma unroll
            for (int j = 0; j < EPG; ++j) {
                int e = e0 + j;
                if (e < cnt) { r[j] = rb[base+e]; s[j] = sb[base+e]; c[j] = cb[base+e]; }
                else         { r[j] = nb0; s[j] = 0; c[j] = 0.f; }
            }
        }

        // interle: Ak[r] is this block's 16KB slice (L1-hot); Bq[s] random
        uint2 ak[EPG], bq[EPG];
        #pragma unroll
        for (int j = 0; j < EPG; ++j) {
            ak[j] = ((const uint2*)Ak)[(size_t)r[j] * 16 + lane];
            bq[j] = ((const uint2*)Bq)[(size_t)s[j] * 16 + lane];
        }

        #pragma unroll
        for (int j = 0; j < EPG; ++j) {
            float A0 = bf16lo(ak[j].x), k0 = bf16hi(ak[j].x);
            float A1 = bf16lo(ak[j].y), k1 = bf16hi(ak[j].y);
            float B0 = bf16lo(bq[j].x), q0 = bf16hi(bq[j].x);
            float B1 = bf16lo(bq[j].y), q1 = bf16hi(bq[j].y);

            float m0 = fmaxf(fmaf(c[j], w0, A0 + B0), 0.f);
            float m1 = fmaxf(fmaf(c[j], w1, A1 + B1), 0.f);

            float d = fmaf(q0, k0, q1 * k1);
            d = dpp_addstep<0xB1>(d);    // xor1 (quad_perm)
            d = dpp_addstep<0x4E>(d);    // xor2 (quad_perm)
            d = dpp_addstep<0x141>(d);   // row_half_mirror
            d = dpp_addstep<0x140>(d);   // row_mirror -> full 16-lane dot

            if (d > -5.f && e0 + j < cnt) {
                float sig = __fdividef(1.f, 1.f + __expf(-d));
                float v0 = m0 * sig, v1 = m1 * sig;
                if (v0 + v1 > 0.f) {     // relu'd, both >=0: skip exact-zero adds
                    int row = r[j] - nb0;
                    atomicAdd(&sagg[row * 33 + 2 * lane],     v0);
                    atomicAdd(&sagg[row * 33 + 2 * lane + 1], v1);
                }
            }
        }
    }
    __syncthreads();

    for (int i = tid; i < ncnt * 32; i += 256) {
        int row = i >> 5, ch = i & 31;
        out[(size_t)(nb0 + row) * 32 + ch] = fmaxf(sagg[row * 33 + ch], 0.f);
    }
}

// ---- fallback path (R8, proven): atomic pk-bf16 scatter + relu widen ----

__global__ __launch_bounds__(256) void edge_kernel(
    const uint32_t* __restrict__ Ak, const uint32_t* __restrict__ Bq,
    const int* __restrict__ senders, const int* __restrict__ receivers,
    const float* __restrict__ couplings, const float* __restrict__ W1,
    uint32_t* __restrict__ agg, int n_edges, int e_half)
{
    int lane = threadIdx.x & 15;
    int sg   = (blockIdx.x * 256 + threadIdx.x) >> 4;
    float w0 = W1[64 * 32 + 2 * lane];
    float w1 = W1[64 * 32 + 2 * lane + 1];
    int e0 = sg * EPG;
    if (e0 >= n_edges) return;

    int r[EPG], s[EPG];
    float c[EPG];

    bool straddle = (e0 < e_half) && (e0 + EPG > e_half);
    if (e0 + EPG <= n_edges && !straddle) {
        #pragma unroll
        for (int v = 0; v < EPG / 4; ++v) {
            vint4 rv = __builtin_nontemporal_load((const vint4*)(receivers + e0) + v);
            vint4 sv = __builtin_nontemporal_load((const vint4*)(senders   + e0) + v);
            r[4*v+0]=rv.x; r[4*v+1]=rv.y; r[4*v+2]=rv.z; r[4*v+3]=rv.w;
            s[4*v+0]=sv.x; s[4*v+1]=sv.y; s[4*v+2]=sv.z; s[4*v+3]=sv.w;
        }
        int cb = (e0 < e_half) ? e0 : e0 - e_half;
        #pragma unroll
        for (int v = 0; v < EPG / 4; ++v) {
            vfloat4 cv = __builtin_nontemporal_load((const vfloat4*)(couplings + cb) + v);
            c[4*v+0]=cv.x; c[4*v+1]=cv.y; c[4*v+2]=cv.z; c[4*v+3]=cv.w;
        }
    } else {
        #pragma unroll
        for (int j = 0; j < EPG; ++j) {
            int e = e0 + j;
            if (e < n_edges) {
                r[j] = receivers[e];
                s[j] = senders[e];
                c[j] = couplings[e < e_half ? e : e - e_half];
            } else { r[j] = 0; s[j] = 0; c[j] = 0.f; }
        }
    }

    uint2 ak[EPG], bq[EPG];
    #pragma unroll
    for (int j = 0; j < EPG; ++j) {
        ak[j] = ((const uint2*)Ak)[(size_t)r[j] * 16 + lane];
        bq[j] = ((const uint2*)Bq)[(size_t)s[j] * 16 + lane];
    }

    #pragma unroll
    for (int j = 0; j < EPG; ++j) {
        float A0 = bf16lo(ak[j].x), k0 = bf16hi(ak[j].x);
        float A1 = bf16lo(ak[j].y), k1 = bf16hi(ak[j].y);
        float B0 = bf16lo(bq[j].x), q0 = bf16hi(bq[j].x);
        float B1 = bf16lo(bq[j].y), q1 = bf16hi(bq[j].y);

        float m0 = fmaxf(fmaf(c[j], w0, A0 + B0), 0.f);
        float m1 = fmaxf(fmaf(c[j], w1, A1 + B1), 0.f);

        float d = fmaf(q0, k0, q1 * k1);
        d += __shfl_xor(d, 1, 64);
        d += __shfl_xor(d, 2, 64);
        d += __shfl_xor(d, 4, 64);
        d += __shfl_xor(d, 8, 64);

        if (d > -5.f && e0 + j < n_edges) {
            float sig = __fdividef(1.f, 1.f + __expf(-d));
            uint32_t val = pack_bf16(m0 * sig, m1 * sig);
            atomic_pk_add_bf16(agg + (size_t)r[j] * 16 + lane, val);
        }
    }
}

__global__ __launch_bounds__(256) void relu_widen_copy(
    const uint2* __restrict__ agg, float4* __restrict__ out, int n4)
{
    int i = blockIdx.x * 256 + threadIdx.x;
    if (i < n4) {
        uint2 v = agg[i];
        float4 o;
        o.x = fmaxf(bf16lo(v.x), 0.f);
        o.y = fmaxf(bf16hi(v.x), 0.f);
        o.z = fmaxf(bf16lo(v.y), 0.f);
        o.w = fmaxf(bf16hi(v.y), 0.f);
        out[i] = o;
    }
}

extern "C" void kernel_launch(void* const* d_in, const int* in_sizes, int n_in,
                              void* d_out, int out_size, void* d_ws, size_t ws_size,
                              hipStream_t stream)
{
    const float* h         = (const float*)d_in[0];
    const float* couplings = (const float*)d_in[1];
    const float* W1        = (const float*)d_in[2];
    const float* b1        = (const float*)d_in[3];
    const float* Wq        = (const float*)d_in[4];
    const float* bq        = (const float*)d_in[5];
    const float* Wk        = (const float*)d_in[6];
    const float* bk        = (const float*)d_in[7];
    const int*   senders   = (const int*)d_in[8];
    const int*   receivers = (const int*)d_in[9];
    float* out = (float*)d_out;

    int n_nodes = in_sizes[0] / 32;
    int e_half  = in_sizes[1];
    int n_edges = in_sizes[8];

    size_t N32 = (size_t)n_nodes * 32;
    int nb = (n_nodes + BSIZE - 1) >> BSHIFT;

    // ws layout (bucketed): Ak | Bq | counts[NBMAX] | bases[NBMAX] | cursor[NBMAX]
    //                       | rb[cap] | sb[cap] | cb[cap]
    uint32_t* Ak = (uint32_t*)d_ws;
    uint32_t* Bq = Ak + N32;
    int* counts  = (int*)(Bq + N32);
    int* bases   = counts + NBMAX;
    int* cursor  = bases + NBMAX;
    int* rb      = cursor + NBMAX;
    int  cap     = n_edges + 8 * NBMAX + 16;
    int* sb      = rb + cap;
    float* cb    = (float*)(sb + cap);
    size_t need  = (size_t)((char*)(cb + cap) - (char*)d_ws);

    if (nb <= NBMAX && ws_size >= need) {
        hipMemsetAsync(counts, 0, NBMAX * sizeof(int), stream);
        node_precompute<<<2048, 256, 0, stream>>>(
            h, W1, b1, Wq, bq, Wk, bk, Ak, Bq,
            (uint4*)nullptr, 0, receivers, n_edges, counts, nb, n_nodes);
        scan_kernel<<<1, 1024, 0, stream>>>(counts, bases, cursor, nb);
        int scb = (n_edges + SC_CHUNK - 1) / SC_CHUNK;
        scatter_kernel<<<scb, 1024, 0, stream>>>(
            senders, receivers, couplings, cursor, rb, sb, cb, n_edges, e_half, nb);
        edge_bucket_kernel<<<nb, 256, 0, stream>>>(
            Ak, Bq, rb, sb, cb, bases, counts, W1, out, n_nodes);
    } else {
        // R8 fallback: Ak | Bq | agg(bf16)
        uint32_t* agg = Bq + N32;
        int n_aggz = (int)(N32 / 8);
        node_precompute<<<2048, 256, 0, stream>>>(
            h, W1, b1, Wq, bq, Wk, bk, Ak, Bq,
            (uint4*)agg, n_aggz, receivers, n_edges, nullptr, 0, n_nodes);
        int nsub    = (n_edges + EPG - 1) / EPG;
        int eblocks = (nsub + 15) / 16;
        edge_kernel<<<eblocks, 256, 0, stream>>>(
            Ak, Bq, senders, receivers, couplings, W1, agg, n_edges, e_half);
        int n4 = (int)(N32 / 4);
        relu_widen_copy<<<(n4 + 255) / 256, 256, 0, stream>>>(
            (const uint2*)agg, (float4*)out, n4);
    }
}

// Round 4
// 555.337 us; speedup vs baseline: 1.2342x; 1.2342x over previous
//
#include <hip/hip_runtime.h>
#include <hip/hip_cooperative_groups.h>
#include <hip/hip_bf16.h>
#include <cstdint>

// AttentionGNNLayer, R12: single cooperative fused kernel (R8-verbatim math).
// R10/R11 post-mortem: bucketed-scatter direction abandoned -- two opaque correctness
// failures, and even its best case barely beats R8 (scatter write-amplification).
// R8 accounting gap: edge 141.5us + precompute ~15 + relu ~5 = ~165us of kernel time
// vs 277us measured -> ~110us of inter-dispatch/launch overhead. R12 fuses the three
// R8 kernels into ONE cooperative launch with grid.sync() at the two dependency
// boundaries. Math/loads/atomics/thresholds identical to the PASSING R8 kernel:
//   per-node A=h@W1a+b1, B=h@W1b, q=h@Wq+bq, k=h@Wk+bk (bf16-packed Ak/Bq)
//   per-edge msg = relu(A[r]+B[s]+c*w1c) * sigmoid(q[s].k[r]), pk-bf16 atomic agg
//   final relu-widen to f32 out.
// Phase 1 reads weights from LDS (not a 64-reg wa/wb file) to keep VGPR low for the
// edge phase's occupancy. Grid sized via occupancy query + downgrade cascade; any
// launch failure falls back to the verbatim R8 3-kernel path (worst case = R8 perf).

#define EPG 8   // edges per 16-lane subgroup

namespace cg = cooperative_groups;

typedef int   vint4   __attribute__((ext_vector_type(4)));
typedef float vfloat4 __attribute__((ext_vector_type(4)));

__device__ __forceinline__ float bf16lo(uint32_t u) {
    uint32_t b = (u & 0xFFFFu) << 16;
    float f; __builtin_memcpy(&f, &b, 4); return f;
}
__device__ __forceinline__ float bf16hi(uint32_t u) {
    uint32_t b = u & 0xFFFF0000u;
    float f; __builtin_memcpy(&f, &b, 4); return f;
}
__device__ __forceinline__ uint32_t pack_bf16(float lo, float hi) {
    __hip_bfloat16 l = __float2bfloat16(lo);
    __hip_bfloat16 h = __float2bfloat16(hi);
    uint16_t lb, hb;
    __builtin_memcpy(&lb, &l, 2);
    __builtin_memcpy(&hb, &h, 2);
    return (uint32_t)lb | ((uint32_t)hb << 16);
}
__device__ __forceinline__ void atomic_pk_add_bf16(uint32_t* addr, uint32_t val) {
    asm volatile("global_atomic_pk_add_bf16 %0, %1, off" :: "v"(addr), "v"(val) : "memory");
}

// ==================== fused cooperative kernel ====================

__global__ __launch_bounds__(256, 4) void fused_kernel(
    const float* __restrict__ h, const float* __restrict__ couplings,
    const float* __restrict__ W1, const float* __restrict__ b1,
    const float* __restrict__ Wq, const float* __restrict__ bq,
    const float* __restrict__ Wk, const float* __restrict__ bk,
    const int* __restrict__ senders, const int* __restrict__ receivers,
    uint32_t* __restrict__ Ak, uint32_t* __restrict__ Bq,
    uint32_t* __restrict__ agg, float4* __restrict__ out,
    int n_nodes, int n_edges, int e_half)
{
    __shared__ float sW[4][32 * 33];   // +1 pad: conflict-free column reads
    int tid = threadIdx.x;

    // ---- phase 1a: stage weights, zero agg ----
    for (int i = tid; i < 1024; i += 256) {
        int j = i >> 5, t = i & 31;
        sW[0][j * 33 + t] = W1[i];          // W1a (receiver part)
        sW[1][j * 33 + t] = W1[1024 + i];   // W1b (sender part)
        sW[2][j * 33 + t] = Wq[i];
        sW[3][j * 33 + t] = Wk[i];
    }
    int n_aggz = (n_nodes * 32) / 8;   // uint4 count covering N32*2 bytes
    uint4* aggz = (uint4*)agg;
    for (int i = blockIdx.x * 256 + tid; i < n_aggz; i += gridDim.x * 256)
        aggz[i] = make_uint4(0u, 0u, 0u, 0u);
    __syncthreads();

    // ---- phase 1b: node precompute (R8-verbatim layout, weights from LDS) ----
    {
        int t    = tid & 31;          // channel
        int wave = tid >> 6;          // 0..3
        int half = wave & 1;          // 0: (A,k)->Ak, 1: (B,q)->Bq
        int sub  = (tid >> 5) & 1;    // group within wave
        int nib  = (wave >> 1) * 2 + sub;   // node slot in block: 0..3

        const float* pwa = &sW[half ? 1 : 0][0];   // W1b : W1a
        const float* pwb = &sW[half ? 2 : 3][0];   // Wq  : Wk
        float ba = half ? 0.f   : b1[t];
        float bb = half ? bq[t] : bk[t];
        uint32_t* dst = half ? Bq : Ak;

        for (int n = blockIdx.x * 4 + nib; n < n_nodes; n += gridDim.x * 4) {
            float hv = h[(size_t)n * 32 + t];
            float aa = ba, ab = bb;
            #pragma unroll
            for (int j = 0; j < 32; ++j) {
                float hj = __shfl(hv, j, 32);
                aa = fmaf(hj, pwa[j * 33 + t], aa);
                ab = fmaf(hj, pwb[j * 33 + t], ab);
            }
            dst[(size_t)n * 32 + t] = pack_bf16(aa, ab);
        }
    }

    __threadfence();
    cg::this_grid().sync();

    // ---- phase 2: edges (R8-verbatim body, grid-strided 8-edge groups) ----
    {
        int lane = tid & 15;
        float w0 = W1[64 * 32 + 2 * lane];   // coupling row (L1-resident)
        float w1 = W1[64 * 32 + 2 * lane + 1];
        int ngroups = (n_edges + EPG - 1) / EPG;
        int gstride = gridDim.x * 16;        // 16-lane groups per sweep

        for (int sg = (blockIdx.x * 256 + tid) >> 4; sg < ngroups; sg += gstride) {
            int e0 = sg * EPG;
            int r[EPG], s[EPG];
            float c[EPG];

            bool straddle = (e0 < e_half) && (e0 + EPG > e_half);
            if (e0 + EPG <= n_edges && !straddle) {
                #pragma unroll
                for (int v = 0; v < EPG / 4; ++v) {
                    vint4 rv = __builtin_nontemporal_load((const vint4*)(receivers + e0) + v);
                    vint4 sv = __builtin_nontemporal_load((const vint4*)(senders   + e0) + v);
                    r[4*v+0]=rv.x; r[4*v+1]=rv.y; r[4*v+2]=rv.z; r[4*v+3]=rv.w;
                    s[4*v+0]=sv.x; s[4*v+1]=sv.y; s[4*v+2]=sv.z; s[4*v+3]=sv.w;
                }
                int cb = (e0 < e_half) ? e0 : e0 - e_half;
                #pragma unroll
                for (int v = 0; v < EPG / 4; ++v) {
                    vfloat4 cv = __builtin_nontemporal_load((const vfloat4*)(couplings + cb) + v);
                    c[4*v+0]=cv.x; c[4*v+1]=cv.y; c[4*v+2]=cv.z; c[4*v+3]=cv.w;
                }
            } else {
                #pragma unroll
                for (int j = 0; j < EPG; ++j) {
                    int e = e0 + j;
                    if (e < n_edges) {
                        r[j] = receivers[e];
                        s[j] = senders[e];
                        c[j] = couplings[e < e_half ? e : e - e_half];
                    } else { r[j] = 0; s[j] = 0; c[j] = 0.f; }
                }
            }

            // interleaved gather issue (R8): compute on edge j starts early
            uint2 ak[EPG], bq2[EPG];
            #pragma unroll
            for (int j = 0; j < EPG; ++j) {
                ak[j]  = ((const uint2*)Ak)[(size_t)r[j] * 16 + lane];
                bq2[j] = ((const uint2*)Bq)[(size_t)s[j] * 16 + lane];
            }

            #pragma unroll
            for (int j = 0; j < EPG; ++j) {
                float A0 = bf16lo(ak[j].x),  k0 = bf16hi(ak[j].x);
                float A1 = bf16lo(ak[j].y),  k1 = bf16hi(ak[j].y);
                float B0 = bf16lo(bq2[j].x), q0 = bf16hi(bq2[j].x);
                float B1 = bf16lo(bq2[j].y), q1 = bf16hi(bq2[j].y);

                float m0 = fmaxf(fmaf(c[j], w0, A0 + B0), 0.f);
                float m1 = fmaxf(fmaf(c[j], w1, A1 + B1), 0.f);

                float d = fmaf(q0, k0, q1 * k1);
                d += __shfl_xor(d, 1, 64);
                d += __shfl_xor(d, 2, 64);
                d += __shfl_xor(d, 4, 64);
                d += __shfl_xor(d, 8, 64);                 // full 16-lane dot

                // sigmoid(d) < 6.7e-3 -> contribution < ~0.013/edge: skip
                if (d > -5.f && e0 + j < n_edges) {
                    float sig = __fdividef(1.f, 1.f + __expf(-d));
                    uint32_t val = pack_bf16(m0 * sig, m1 * sig);
                    atomic_pk_add_bf16(agg + (size_t)r[j] * 16 + lane, val);
                }
            }
        }
    }

    __threadfence();
    cg::this_grid().sync();

    // ---- phase 3: relu widen (R8-verbatim math, grid-strided) ----
    {
        int n4 = (n_nodes * 32) / 4;
        const uint2* aggv = (const uint2*)agg;
        for (int i = blockIdx.x * 256 + tid; i < n4; i += gridDim.x * 256) {
            uint2 v = aggv[i];
            float4 o;
            o.x = fmaxf(bf16lo(v.x), 0.f);
            o.y = fmaxf(bf16hi(v.x), 0.f);
            o.z = fmaxf(bf16lo(v.y), 0.f);
            o.w = fmaxf(bf16hi(v.y), 0.f);
            out[i] = o;
        }
    }
}

// ==================== fallback: R8-verbatim 3-kernel path ====================

__global__ __launch_bounds__(256) void node_precompute(
    const float* __restrict__ h, const float* __restrict__ W1,
    const float* __restrict__ b1, const float* __restrict__ Wq,
    const float* __restrict__ bq, const float* __restrict__ Wk,
    const float* __restrict__ bk,
    uint32_t* __restrict__ Ak, uint32_t* __restrict__ Bq,
    uint4* __restrict__ aggz, int n_aggz, int n_nodes)
{
    for (int i = blockIdx.x * 256 + threadIdx.x; i < n_aggz; i += gridDim.x * 256)
        aggz[i] = make_uint4(0u, 0u, 0u, 0u);

    __shared__ float sW[4][32 * 33];
    int tid = threadIdx.x;
    for (int i = tid; i < 1024; i += 256) {
        int j = i >> 5, t = i & 31;
        sW[0][j * 33 + t] = W1[i];
        sW[1][j * 33 + t] = W1[1024 + i];
        sW[2][j * 33 + t] = Wq[i];
        sW[3][j * 33 + t] = Wk[i];
    }
    __syncthreads();

    int t    = tid & 31;
    int wave = tid >> 6;
    int half = wave & 1;
    int sub  = (tid >> 5) & 1;
    int nib  = (wave >> 1) * 2 + sub;

    int ma = half ? 1 : 0;
    int mb = half ? 2 : 3;
    float wa[32], wb[32];
    #pragma unroll
    for (int j = 0; j < 32; ++j) {
        wa[j] = sW[ma][j * 33 + t];
        wb[j] = sW[mb][j * 33 + t];
    }
    float ba = half ? 0.f    : b1[t];
    float bb = half ? bq[t]  : bk[t];
    uint32_t* dst = half ? Bq : Ak;

    for (int n = blockIdx.x * 4 + nib; n < n_nodes; n += gridDim.x * 4) {
        float hv = h[n * 32 + t];
        float aa = ba, ab = bb;
        #pragma unroll
        for (int j = 0; j < 32; ++j) {
            float hj = __shfl(hv, j, 32);
            aa = fmaf(hj, wa[j], aa);
            ab = fmaf(hj, wb[j], ab);
        }
        dst[n * 32 + t] = pack_bf16(aa, ab);
    }
}

__global__ __launch_bounds__(256) void edge_kernel(
    const uint32_t* __restrict__ Ak, const uint32_t* __restrict__ Bq,
    const int* __restrict__ senders, const int* __restrict__ receivers,
    const float* __restrict__ couplings, const float* __restrict__ W1,
    uint32_t* __restrict__ agg, int n_edges, int e_half)
{
    int lane = threadIdx.x & 15;
    int sg   = (blockIdx.x * 256 + threadIdx.x) >> 4;
    float w0 = W1[64 * 32 + 2 * lane];
    float w1 = W1[64 * 32 + 2 * lane + 1];
    int e0 = sg * EPG;
    if (e0 >= n_edges) return;

    int r[EPG], s[EPG];
    float c[EPG];

    bool straddle = (e0 < e_half) && (e0 + EPG > e_half);
    if (e0 + EPG <= n_edges && !straddle) {
        #pragma unroll
        for (int v = 0; v < EPG / 4; ++v) {
            vint4 rv = __builtin_nontemporal_load((const vint4*)(receivers + e0) + v);
            vint4 sv = __builtin_nontemporal_load((const vint4*)(senders   + e0) + v);
            r[4*v+0]=rv.x; r[4*v+1]=rv.y; r[4*v+2]=rv.z; r[4*v+3]=rv.w;
            s[4*v+0]=sv.x; s[4*v+1]=sv.y; s[4*v+2]=sv.z; s[4*v+3]=sv.w;
        }
        int cb = (e0 < e_half) ? e0 : e0 - e_half;
        #pragma unroll
        for (int v = 0; v < EPG / 4; ++v) {
            vfloat4 cv = __builtin_nontemporal_load((const vfloat4*)(couplings + cb) + v);
            c[4*v+0]=cv.x; c[4*v+1]=cv.y; c[4*v+2]=cv.z; c[4*v+3]=cv.w;
        }
    } else {
        #pragma unroll
        for (int j = 0; j < EPG; ++j) {
            int e = e0 + j;
            if (e < n_edges) {
                r[j] = receivers[e];
                s[j] = senders[e];
                c[j] = couplings[e < e_half ? e : e - e_half];
            } else { r[j] = 0; s[j] = 0; c[j] = 0.f; }
        }
    }

    uint2 ak[EPG], bq[EPG];
    #pragma unroll
    for (int j = 0; j < EPG; ++j) {
        ak[j] = ((const uint2*)Ak)[(size_t)r[j] * 16 + lane];
        bq[j] = ((const uint2*)Bq)[(size_t)s[j] * 16 + lane];
    }

    #pragma unroll
    for (int j = 0; j < EPG; ++j) {
        float A0 = bf16lo(ak[j].x), k0 = bf16hi(ak[j].x);
        float A1 = bf16lo(ak[j].y), k1 = bf16hi(ak[j].y);
        float B0 = bf16lo(bq[j].x), q0 = bf16hi(bq[j].x);
        float B1 = bf16lo(bq[j].y), q1 = bf16hi(bq[j].y);

        float m0 = fmaxf(fmaf(c[j], w0, A0 + B0), 0.f);
        float m1 = fmaxf(fmaf(c[j], w1, A1 + B1), 0.f);

        float d = fmaf(q0, k0, q1 * k1);
        d += __shfl_xor(d, 1, 64);
        d += __shfl_xor(d, 2, 64);
        d += __shfl_xor(d, 4, 64);
        d += __shfl_xor(d, 8, 64);

        if (d > -5.f && e0 + j < n_edges) {
            float sig = __fdividef(1.f, 1.f + __expf(-d));
            uint32_t val = pack_bf16(m0 * sig, m1 * sig);
            atomic_pk_add_bf16(agg + (size_t)r[j] * 16 + lane, val);
        }
    }
}

__global__ __launch_bounds__(256) void relu_widen_copy(
    const uint2* __restrict__ agg, float4* __restrict__ out, int n4)
{
    int i = blockIdx.x * 256 + threadIdx.x;
    if (i < n4) {
        uint2 v = agg[i];
        float4 o;
        o.x = fmaxf(bf16lo(v.x), 0.f);
        o.y = fmaxf(bf16hi(v.x), 0.f);
        o.z = fmaxf(bf16lo(v.y), 0.f);
        o.w = fmaxf(bf16hi(v.y), 0.f);
        out[i] = o;
    }
}

extern "C" void kernel_launch(void* const* d_in, const int* in_sizes, int n_in,
                              void* d_out, int out_size, void* d_ws, size_t ws_size,
                              hipStream_t stream)
{
    const float* h         = (const float*)d_in[0];
    const float* couplings = (const float*)d_in[1];
    const float* W1        = (const float*)d_in[2];
    const float* b1        = (const float*)d_in[3];
    const float* Wq        = (const float*)d_in[4];
    const float* bq        = (const float*)d_in[5];
    const float* Wk        = (const float*)d_in[6];
    const float* bk        = (const float*)d_in[7];
    const int*   senders   = (const int*)d_in[8];
    const int*   receivers = (const int*)d_in[9];
    float*  out  = (float*)d_out;
    float4* out4 = (float4*)d_out;

    int n_nodes = in_sizes[0] / 32;
    int e_half  = in_sizes[1];
    int n_edges = in_sizes[8];

    size_t N32 = (size_t)n_nodes * 32;

    // ws layout: Ak (u32 x N32) | Bq (u32 x N32) | agg (bf16 x N32 = N32/2 u32)
    uint32_t* Ak  = (uint32_t*)d_ws;
    uint32_t* Bq  = Ak + N32;
    uint32_t* agg = Bq + N32;

    // ---- cooperative fused launch; fall back to R8 3-kernel path on any error ----
    bool done = false;
    int blocks_per_cu = 0;
    hipError_t qerr = hipOccupancyMaxActiveBlocksPerMultiprocessor(
        &blocks_per_cu, fused_kernel, 256, 0);

    void* args[] = {
        (void*)&h, (void*)&couplings, (void*)&W1, (void*)&b1,
        (void*)&Wq, (void*)&bq, (void*)&Wk, (void*)&bk,
        (void*)&senders, (void*)&receivers,
        (void*)&Ak, (void*)&Bq, (void*)&agg, (void*)&out4,
        (void*)&n_nodes, (void*)&n_edges, (void*)&e_half
    };

    int cands[4];
    int ncand = 0;
    if (qerr == hipSuccess && blocks_per_cu > 0)
        cands[ncand++] = blocks_per_cu * 256;   // 256 CUs on MI355X
    cands[ncand++] = 2048;
    cands[ncand++] = 1024;
    cands[ncand++] = 512;

    for (int i = 0; i < ncand && !done; ++i) {
        int g = cands[i];
        if (g <= 0) continue;
        if (i > 0 && ncand > 1 && g >= cands[0] && qerr == hipSuccess) continue;
        hipError_t lerr = hipLaunchCooperativeKernel(
            (void*)fused_kernel, dim3(g), dim3(256), args, 0, stream);
        if (lerr == hipSuccess) done = true;
    }

    if (!done) {
        // R8-verbatim fallback (proven 277us)
        int n_aggz = (int)(N32 / 8);
        node_precompute<<<2048, 256, 0, stream>>>(
            h, W1, b1, Wq, bq, Wk, bk, Ak, Bq, (uint4*)agg, n_aggz, n_nodes);
        int nsub    = (n_edges + EPG - 1) / EPG;
        int eblocks = (nsub + 15) / 16;
        edge_kernel<<<eblocks, 256, 0, stream>>>(
            Ak, Bq, senders, receivers, couplings, W1, agg, n_edges, e_half);
        int n4 = (int)(N32 / 4);
        relu_widen_copy<<<(n4 + 255) / 256, 256, 0, stream>>>(
            (const uint2*)agg, (float4*)out, n4);
    }
}

// Round 5
// 279.418 us; speedup vs baseline: 2.4530x; 1.9875x over previous
//
#include <hip/hip_runtime.h>
#include <hip/hip_bf16.h>
#include <cstdint>

// AttentionGNNLayer factored form (R13 = R8-verbatim + exact-zero atomic skip):
//   per-node A=h@W1a+b1, B=h@W1b, q=h@Wq+bq, k=h@Wk+bk  (W1a=W1 rows 0..31, W1b=rows 32..63)
//   per-edge msg = relu(A[r]+B[s]+c*w1c) * sigmoid(q[s]·k[r]), aggregated by receiver.
// Session ledger: R9-R11 (receiver bucketing) = 1 slow pass + 2 opaque fails; R12
// (cooperative fusion) = 555us regression (fused kernel 648us, occ 48%, VALUBusy/occ
// 0.29 vs R8's 0.88 -- small specialized kernels win; the ~110us dispatch gap is not
// removable by fusion). R13 re-banks the proven R8 structure (276.9us) with ONE
// bit-exact delta: skip atomics when both relu'd message channels are exactly 0
// (v0,v1 >= 0, so v0+v1>0 is the precise non-noop condition; same guard passed in R9).
// DIAGNOSTIC: if WRITE_SIZE (161.9MB) drops ~25% -> atomics are byte/sector-bound ->
// R14 compresses gather rows (fp8). If flat -> line-bound -> near structural ceiling.

#define EPG 8   // edges per 16-lane subgroup (edge kernel)

typedef int   vint4   __attribute__((ext_vector_type(4)));
typedef float vfloat4 __attribute__((ext_vector_type(4)));

__device__ __forceinline__ float bf16lo(uint32_t u) {
    uint32_t b = (u & 0xFFFFu) << 16;
    float f; __builtin_memcpy(&f, &b, 4); return f;
}
__device__ __forceinline__ float bf16hi(uint32_t u) {
    uint32_t b = u & 0xFFFF0000u;
    float f; __builtin_memcpy(&f, &b, 4); return f;
}
__device__ __forceinline__ uint32_t pack_bf16(float lo, float hi) {
    __hip_bfloat16 l = __float2bfloat16(lo);
    __hip_bfloat16 h = __float2bfloat16(hi);
    uint16_t lb, hb;
    __builtin_memcpy(&lb, &l, 2);
    __builtin_memcpy(&hb, &h, 2);
    return (uint32_t)lb | ((uint32_t)hb << 16);
}

__device__ __forceinline__ void atomic_pk_add_bf16(uint32_t* addr, uint32_t val) {
    // packed 2x bf16 atomic add; fire-and-forget (no return)
    asm volatile("global_atomic_pk_add_bf16 %0, %1, off" :: "v"(addr), "v"(val) : "memory");
}

// ---- node precompute: weight columns in registers, wave-specialized; also zeros agg ----
// Block = 256 threads = 4 waves. Waves 0,2: (A,k)->Ak. Waves 1,3: (B,q)->Bq.

__global__ __launch_bounds__(256) void node_precompute(
    const float* __restrict__ h, const float* __restrict__ W1,
    const float* __restrict__ b1, const float* __restrict__ Wq,
    const float* __restrict__ bq, const float* __restrict__ Wk,
    const float* __restrict__ bk,
    uint32_t* __restrict__ Ak, uint32_t* __restrict__ Bq,
    uint4* __restrict__ aggz, int n_aggz, int n_nodes)
{
    // zero the bf16 accumulator (folded dispatch)
    for (int i = blockIdx.x * 256 + threadIdx.x; i < n_aggz; i += gridDim.x * 256)
        aggz[i] = make_uint4(0u, 0u, 0u, 0u);

    __shared__ float sW[4][32 * 33];   // +1 pad: conflict-free column reads
    int tid = threadIdx.x;
    for (int i = tid; i < 1024; i += 256) {
        int j = i >> 5, t = i & 31;
        sW[0][j * 33 + t] = W1[i];          // W1a (receiver part)
        sW[1][j * 33 + t] = W1[1024 + i];   // W1b (sender part)
        sW[2][j * 33 + t] = Wq[i];
        sW[3][j * 33 + t] = Wk[i];
    }
    __syncthreads();

    int t    = tid & 31;          // channel
    int wave = tid >> 6;          // 0..3
    int half = wave & 1;          // 0: (A,k)->Ak, 1: (B,q)->Bq
    int sub  = (tid >> 5) & 1;    // group within wave
    int nib  = (wave >> 1) * 2 + sub;   // node slot in block: 0..3

    int ma = half ? 1 : 0;        // W1b : W1a
    int mb = half ? 2 : 3;        // Wq  : Wk
    float wa[32], wb[32];
    #pragma unroll
    for (int j = 0; j < 32; ++j) {
        wa[j] = sW[ma][j * 33 + t];
        wb[j] = sW[mb][j * 33 + t];
    }
    float ba = half ? 0.f    : b1[t];
    float bb = half ? bq[t]  : bk[t];
    uint32_t* dst = half ? Bq : Ak;

    for (int n = blockIdx.x * 4 + nib; n < n_nodes; n += gridDim.x * 4) {
        float hv = h[n * 32 + t];
        float aa = ba, ab = bb;
        #pragma unroll
        for (int j = 0; j < 32; ++j) {
            float hj = __shfl(hv, j, 32);
            aa = fmaf(hj, wa[j], aa);
            ab = fmaf(hj, wb[j], ab);
        }
        dst[n * 32 + t] = pack_bf16(aa, ab);
    }
}

// ---- edge kernel: 16 lanes = one edge (2 channels/lane); 8 edges batched ----

__global__ __launch_bounds__(256) void edge_kernel(
    const uint32_t* __restrict__ Ak, const uint32_t* __restrict__ Bq,
    const int* __restrict__ senders, const int* __restrict__ receivers,
    const float* __restrict__ couplings, const float* __restrict__ W1,
    uint32_t* __restrict__ agg, int n_edges, int e_half)
{
    int lane = threadIdx.x & 15;                       // lane within edge
    int sg   = (blockIdx.x * 256 + threadIdx.x) >> 4;  // global 16-lane subgroup id
    float w0 = W1[64 * 32 + 2 * lane];                 // coupling row (L1-resident)
    float w1 = W1[64 * 32 + 2 * lane + 1];
    int e0 = sg * EPG;
    if (e0 >= n_edges) return;

    int r[EPG], s[EPG];
    float c[EPG];

    bool straddle = (e0 < e_half) && (e0 + EPG > e_half);
    if (e0 + EPG <= n_edges && !straddle) {
        // nontemporal: streamed once, keep out of caches so gathers stay resident
        #pragma unroll
        for (int v = 0; v < EPG / 4; ++v) {
            vint4 rv = __builtin_nontemporal_load((const vint4*)(receivers + e0) + v);
            vint4 sv = __builtin_nontemporal_load((const vint4*)(senders   + e0) + v);
            r[4*v+0]=rv.x; r[4*v+1]=rv.y; r[4*v+2]=rv.z; r[4*v+3]=rv.w;
            s[4*v+0]=sv.x; s[4*v+1]=sv.y; s[4*v+2]=sv.z; s[4*v+3]=sv.w;
        }
        int cb = (e0 < e_half) ? e0 : e0 - e_half;
        #pragma unroll
        for (int v = 0; v < EPG / 4; ++v) {
            vfloat4 cv = __builtin_nontemporal_load((const vfloat4*)(couplings + cb) + v);
            c[4*v+0]=cv.x; c[4*v+1]=cv.y; c[4*v+2]=cv.z; c[4*v+3]=cv.w;
        }
    } else {
        #pragma unroll
        for (int j = 0; j < EPG; ++j) {
            int e = e0 + j;
            if (e < n_edges) {
                r[j] = receivers[e];
                s[j] = senders[e];
                c[j] = couplings[e < e_half ? e : e - e_half];
            } else { r[j] = 0; s[j] = 0; c[j] = 0.f; }
        }
    }

    // interleaved gather issue: compute on edge j can start after 2(j+1) retirements
    uint2 ak[EPG], bq[EPG];
    #pragma unroll
    for (int j = 0; j < EPG; ++j) {
        ak[j] = ((const uint2*)Ak)[(size_t)r[j] * 16 + lane];
        bq[j] = ((const uint2*)Bq)[(size_t)s[j] * 16 + lane];
    }

    #pragma unroll
    for (int j = 0; j < EPG; ++j) {
        float A0 = bf16lo(ak[j].x), k0 = bf16hi(ak[j].x);
        float A1 = bf16lo(ak[j].y), k1 = bf16hi(ak[j].y);
        float B0 = bf16lo(bq[j].x), q0 = bf16hi(bq[j].x);
        float B1 = bf16lo(bq[j].y), q1 = bf16hi(bq[j].y);

        float m0 = fmaxf(fmaf(c[j], w0, A0 + B0), 0.f);
        float m1 = fmaxf(fmaf(c[j], w1, A1 + B1), 0.f);

        float d = fmaf(q0, k0, q1 * k1);
        d += __shfl_xor(d, 1, 64);
        d += __shfl_xor(d, 2, 64);
        d += __shfl_xor(d, 4, 64);
        d += __shfl_xor(d, 8, 64);                     // full 16-lane dot

        // sigmoid(d) < 6.7e-3 -> contribution < ~0.013/edge: skip the atomic
        if (d > -5.f && e0 + j < n_edges) {
            float sig = __fdividef(1.f, 1.f + __expf(-d));
            float v0 = m0 * sig, v1 = m1 * sig;
            // exact-zero skip: v0,v1 >= 0 (relu'd * sigmoid>0), so v0+v1==0
            // iff both channels are exactly 0 -> the pk-add would be a no-op.
            if (v0 + v1 > 0.f) {
                uint32_t val = pack_bf16(v0, v1);
                // ONE 64-B-span packed-bf16 atomic per edge (lanes with payload)
                atomic_pk_add_bf16(agg + (size_t)r[j] * 16 + lane, val);
            }
        }
    }
}

__global__ __launch_bounds__(256) void relu_widen_copy(
    const uint2* __restrict__ agg, float4* __restrict__ out, int n4)
{
    int i = blockIdx.x * 256 + threadIdx.x;
    if (i < n4) {
        uint2 v = agg[i];
        float4 o;
        o.x = fmaxf(bf16lo(v.x), 0.f);
        o.y = fmaxf(bf16hi(v.x), 0.f);
        o.z = fmaxf(bf16lo(v.y), 0.f);
        o.w = fmaxf(bf16hi(v.y), 0.f);
        out[i] = o;
    }
}

extern "C" void kernel_launch(void* const* d_in, const int* in_sizes, int n_in,
                              void* d_out, int out_size, void* d_ws, size_t ws_size,
                              hipStream_t stream)
{
    const float* h         = (const float*)d_in[0];
    const float* couplings = (const float*)d_in[1];
    const float* W1        = (const float*)d_in[2];
    const float* b1        = (const float*)d_in[3];
    const float* Wq        = (const float*)d_in[4];
    const float* bq        = (const float*)d_in[5];
    const float* Wk        = (const float*)d_in[6];
    const float* bk        = (const float*)d_in[7];
    const int*   senders   = (const int*)d_in[8];
    const int*   receivers = (const int*)d_in[9];
    float* out = (float*)d_out;

    int n_nodes = in_sizes[0] / 32;
    int e_half  = in_sizes[1];
    int n_edges = in_sizes[8];

    size_t N32 = (size_t)n_nodes * 32;

    // ws layout: Ak (u32 x N32) | Bq (u32 x N32) | agg (bf16 x N32 = N32/2 u32)
    uint32_t* Ak  = (uint32_t*)d_ws;
    uint32_t* Bq  = Ak + N32;
    uint32_t* agg = Bq + N32;
    int n_aggz = (int)(N32 / 8);   // uint4 count covering N32*2 bytes

    node_precompute<<<2048, 256, 0, stream>>>(
        h, W1, b1, Wq, bq, Wk, bk, Ak, Bq, (uint4*)agg, n_aggz, n_nodes);

    int nsub    = (n_edges + EPG - 1) / EPG;   // 16-lane subgroups
    int eblocks = (nsub + 15) / 16;            // 16 subgroups per 256-thread block
    edge_kernel<<<eblocks, 256, 0, stream>>>(
        Ak, Bq, senders, receivers, couplings, W1, agg, n_edges, e_half);

    int n4 = (int)(N32 / 4);
    relu_widen_copy<<<(n4 + 255) / 256, 256, 0, stream>>>(
        (const uint2*)agg, (float4*)out, n4);
}

// Round 6
// 276.600 us; speedup vs baseline: 2.4780x; 1.0102x over previous
//
#include <hip/hip_runtime.h>
#include <hip/hip_bf16.h>
#include <hip/hip_fp8.h>
#include <cstdint>

// AttentionGNNLayer, R14: R8 structure + fp8(e4m3) compression of the Bq gather row.
//   per-node A=h@W1a+b1, B=h@W1b, q=h@Wq+bq, k=h@Wk+bk
//   per-edge msg = relu(A[r]+B[s]+c*w1c) * sigmoid(q[s]·k[r]), pk-bf16 atomic agg.
// Ledger: R9-R11 bucketing (1 slow pass, 2 fails) abandoned; R12 coop fusion = 2x
// regression; R13 zero-skip probe PROVED atomics are line-granular (WRITE flat at
// 161.85MB = surviving-edges x 64B) and edge kernel is throughput- not latency-bound
// (occ 69->50.6% with dur unchanged). Edge cost model: ~5 line-trans/edge =
// 2(Ak 128B) + 2(Bq 128B) + 1(atomic RMW line). R14 shrinks Bq rows to 64B (=1 line)
// via fp8: [B0 q0 B1 q1] bytes per lane-word, HW cvt (v_cvt_f32_fp8). Ak stays bf16
// so the q.k dot only takes q-side quantization (sigma_dd~0.14 vs d sigma~5.7).
// R13's per-lane zero-skip reverted (proved no-op at line granularity).
// DIAGNOSTIC: edge dur -20% -> transaction-bound confirmed -> R15 = fp8 Ak too (4->3).
//             edge dur flat -> atomic-RMW-bound -> skip-ladder or ceiling.

#define EPG 8   // edges per 16-lane subgroup (edge kernel)

typedef int   vint4   __attribute__((ext_vector_type(4)));
typedef float vfloat4 __attribute__((ext_vector_type(4)));

__device__ __forceinline__ float bf16lo(uint32_t u) {
    uint32_t b = (u & 0xFFFFu) << 16;
    float f; __builtin_memcpy(&f, &b, 4); return f;
}
__device__ __forceinline__ float bf16hi(uint32_t u) {
    uint32_t b = u & 0xFFFF0000u;
    float f; __builtin_memcpy(&f, &b, 4); return f;
}
__device__ __forceinline__ uint32_t pack_bf16(float lo, float hi) {
    __hip_bfloat16 l = __float2bfloat16(lo);
    __hip_bfloat16 h = __float2bfloat16(hi);
    uint16_t lb, hb;
    __builtin_memcpy(&lb, &l, 2);
    __builtin_memcpy(&hb, &h, 2);
    return (uint32_t)lb | ((uint32_t)hb << 16);
}

__device__ __forceinline__ void atomic_pk_add_bf16(uint32_t* addr, uint32_t val) {
    // packed 2x bf16 atomic add; fire-and-forget (no return)
    asm volatile("global_atomic_pk_add_bf16 %0, %1, off" :: "v"(addr), "v"(val) : "memory");
}

// ---- fp8 e4m3 (OCP on gfx950) encode/decode: HW converters, header fallback ----
__device__ __forceinline__ uint32_t fp8_pk2(float a, float b) {
#if __has_builtin(__builtin_amdgcn_cvt_pk_fp8_f32)
    return (uint32_t)__builtin_amdgcn_cvt_pk_fp8_f32(a, b, 0, false) & 0xFFFFu;
#else
    __hip_fp8_e4m3 x(a), y(b);
    return (uint32_t)x.__x | ((uint32_t)y.__x << 8);
#endif
}
template<int SEL>
__device__ __forceinline__ float fp8_dec(uint32_t w) {
#if __has_builtin(__builtin_amdgcn_cvt_f32_fp8)
    return __builtin_amdgcn_cvt_f32_fp8(w, SEL);
#else
    __hip_fp8_e4m3 v; v.__x = (uint8_t)(w >> (8 * SEL)); return (float)v;
#endif
}

// ---- node precompute: weight columns in registers, wave-specialized; zeros agg ----
// Block = 256 threads = 4 waves. Waves 0,2: (A,k)->Ak bf16 pairs (128B rows).
// Waves 1,3: (B,q)->Bq8 fp8 quads (64B rows: word l = [B_2l q_2l B_2l+1 q_2l+1]).

__global__ __launch_bounds__(256) void node_precompute(
    const float* __restrict__ h, const float* __restrict__ W1,
    const float* __restrict__ b1, const float* __restrict__ Wq,
    const float* __restrict__ bq, const float* __restrict__ Wk,
    const float* __restrict__ bk,
    uint32_t* __restrict__ Ak, uint32_t* __restrict__ Bq8,
    uint4* __restrict__ aggz, int n_aggz, int n_nodes)
{
    // zero the bf16 accumulator (folded dispatch)
    for (int i = blockIdx.x * 256 + threadIdx.x; i < n_aggz; i += gridDim.x * 256)
        aggz[i] = make_uint4(0u, 0u, 0u, 0u);

    __shared__ float sW[4][32 * 33];   // +1 pad: conflict-free column reads
    int tid = threadIdx.x;
    for (int i = tid; i < 1024; i += 256) {
        int j = i >> 5, t = i & 31;
        sW[0][j * 33 + t] = W1[i];          // W1a (receiver part)
        sW[1][j * 33 + t] = W1[1024 + i];   // W1b (sender part)
        sW[2][j * 33 + t] = Wq[i];
        sW[3][j * 33 + t] = Wk[i];
    }
    __syncthreads();

    int t    = tid & 31;          // channel
    int wave = tid >> 6;          // 0..3
    int half = wave & 1;          // 0: (A,k)->Ak, 1: (B,q)->Bq8
    int sub  = (tid >> 5) & 1;    // group within wave
    int nib  = (wave >> 1) * 2 + sub;   // node slot in block: 0..3

    int ma = half ? 1 : 0;        // W1b : W1a
    int mb = half ? 2 : 3;        // Wq  : Wk
    float wa[32], wb[32];
    #pragma unroll
    for (int j = 0; j < 32; ++j) {
        wa[j] = sW[ma][j * 33 + t];
        wb[j] = sW[mb][j * 33 + t];
    }
    float ba = half ? 0.f    : b1[t];
    float bb = half ? bq[t]  : bk[t];

    int il = 2 * (t & 15);        // source lane pair (within 32-lane group)

    for (int n = blockIdx.x * 4 + nib; n < n_nodes; n += gridDim.x * 4) {
        float hv = h[(size_t)n * 32 + t];
        float aa = ba, ab = bb;
        #pragma unroll
        for (int j = 0; j < 32; ++j) {
            float hj = __shfl(hv, j, 32);
            aa = fmaf(hj, wa[j], aa);
            ab = fmaf(hj, wb[j], ab);
        }
        if (!half) {
            Ak[(size_t)n * 32 + t] = pack_bf16(aa, ab);   // [A_t | k_t] bf16
        } else {
            uint32_t pk = fp8_pk2(aa, ab);                // [fp8(B_t) | fp8(q_t)]
            uint32_t lo = __shfl(pk, il,     32);
            uint32_t hi = __shfl(pk, il + 1, 32);
            if (t < 16)
                Bq8[(size_t)n * 16 + t] = (lo & 0xFFFFu) | (hi << 16);
        }
    }
}

// ---- edge kernel: 16 lanes = one edge (2 channels/lane); 8 edges batched ----

__global__ __launch_bounds__(256) void edge_kernel(
    const uint32_t* __restrict__ Ak, const uint32_t* __restrict__ Bq8,
    const int* __restrict__ senders, const int* __restrict__ receivers,
    const float* __restrict__ couplings, const float* __restrict__ W1,
    uint32_t* __restrict__ agg, int n_edges, int e_half)
{
    int lane = threadIdx.x & 15;                       // lane within edge
    int sg   = (blockIdx.x * 256 + threadIdx.x) >> 4;  // global 16-lane subgroup id
    float w0 = W1[64 * 32 + 2 * lane];                 // coupling row (L1-resident)
    float w1 = W1[64 * 32 + 2 * lane + 1];
    int e0 = sg * EPG;
    if (e0 >= n_edges) return;

    int r[EPG], s[EPG];
    float c[EPG];

    bool straddle = (e0 < e_half) && (e0 + EPG > e_half);
    if (e0 + EPG <= n_edges && !straddle) {
        // nontemporal: streamed once, keep out of caches so gathers stay resident
        #pragma unroll
        for (int v = 0; v < EPG / 4; ++v) {
            vint4 rv = __builtin_nontemporal_load((const vint4*)(receivers + e0) + v);
            vint4 sv = __builtin_nontemporal_load((const vint4*)(senders   + e0) + v);
            r[4*v+0]=rv.x; r[4*v+1]=rv.y; r[4*v+2]=rv.z; r[4*v+3]=rv.w;
            s[4*v+0]=sv.x; s[4*v+1]=sv.y; s[4*v+2]=sv.z; s[4*v+3]=sv.w;
        }
        int cb = (e0 < e_half) ? e0 : e0 - e_half;
        #pragma unroll
        for (int v = 0; v < EPG / 4; ++v) {
            vfloat4 cv = __builtin_nontemporal_load((const vfloat4*)(couplings + cb) + v);
            c[4*v+0]=cv.x; c[4*v+1]=cv.y; c[4*v+2]=cv.z; c[4*v+3]=cv.w;
        }
    } else {
        #pragma unroll
        for (int j = 0; j < EPG; ++j) {
            int e = e0 + j;
            if (e < n_edges) {
                r[j] = receivers[e];
                s[j] = senders[e];
                c[j] = couplings[e < e_half ? e : e - e_half];
            } else { r[j] = 0; s[j] = 0; c[j] = 0.f; }
        }
    }

    // interleaved gather issue: Ak row 128B (2 lines), Bq8 row 64B (1 line)
    uint2 ak[EPG]; uint32_t bw[EPG];
    #pragma unroll
    for (int j = 0; j < EPG; ++j) {
        ak[j] = ((const uint2*)Ak)[(size_t)r[j] * 16 + lane];
        bw[j] = Bq8[(size_t)s[j] * 16 + lane];
    }

    #pragma unroll
    for (int j = 0; j < EPG; ++j) {
        float A0 = bf16lo(ak[j].x), k0 = bf16hi(ak[j].x);
        float A1 = bf16lo(ak[j].y), k1 = bf16hi(ak[j].y);
        float B0 = fp8_dec<0>(bw[j]), q0 = fp8_dec<1>(bw[j]);
        float B1 = fp8_dec<2>(bw[j]), q1 = fp8_dec<3>(bw[j]);

        float m0 = fmaxf(fmaf(c[j], w0, A0 + B0), 0.f);
        float m1 = fmaxf(fmaf(c[j], w1, A1 + B1), 0.f);

        float d = fmaf(q0, k0, q1 * k1);
        d += __shfl_xor(d, 1, 64);
        d += __shfl_xor(d, 2, 64);
        d += __shfl_xor(d, 4, 64);
        d += __shfl_xor(d, 8, 64);                     // full 16-lane dot

        // sigmoid(d) < 6.7e-3 -> contribution < ~0.013/edge: skip the atomic
        if (d > -5.f && e0 + j < n_edges) {
            float sig = __fdividef(1.f, 1.f + __expf(-d));
            uint32_t val = pack_bf16(m0 * sig, m1 * sig);
            // ONE 64-B-span packed-bf16 atomic per edge
            atomic_pk_add_bf16(agg + (size_t)r[j] * 16 + lane, val);
        }
    }
}

__global__ __launch_bounds__(256) void relu_widen_copy(
    const uint2* __restrict__ agg, float4* __restrict__ out, int n4)
{
    int i = blockIdx.x * 256 + threadIdx.x;
    if (i < n4) {
        uint2 v = agg[i];
        float4 o;
        o.x = fmaxf(bf16lo(v.x), 0.f);
        o.y = fmaxf(bf16hi(v.x), 0.f);
        o.z = fmaxf(bf16lo(v.y), 0.f);
        o.w = fmaxf(bf16hi(v.y), 0.f);
        out[i] = o;
    }
}

extern "C" void kernel_launch(void* const* d_in, const int* in_sizes, int n_in,
                              void* d_out, int out_size, void* d_ws, size_t ws_size,
                              hipStream_t stream)
{
    const float* h         = (const float*)d_in[0];
    const float* couplings = (const float*)d_in[1];
    const float* W1        = (const float*)d_in[2];
    const float* b1        = (const float*)d_in[3];
    const float* Wq        = (const float*)d_in[4];
    const float* bq        = (const float*)d_in[5];
    const float* Wk        = (const float*)d_in[6];
    const float* bk        = (const float*)d_in[7];
    const int*   senders   = (const int*)d_in[8];
    const int*   receivers = (const int*)d_in[9];
    float* out = (float*)d_out;

    int n_nodes = in_sizes[0] / 32;
    int e_half  = in_sizes[1];
    int n_edges = in_sizes[8];

    size_t N32 = (size_t)n_nodes * 32;

    // ws layout: Ak (u32 x N32) | Bq8 (u32 x N32/2) | agg (bf16 x N32 = N32/2 u32)
    uint32_t* Ak   = (uint32_t*)d_ws;
    uint32_t* Bq8  = Ak + N32;
    uint32_t* agg  = Bq8 + N32 / 2;
    int n_aggz = (int)(N32 / 8);   // uint4 count covering N32*2 bytes

    node_precompute<<<2048, 256, 0, stream>>>(
        h, W1, b1, Wq, bq, Wk, bk, Ak, Bq8, (uint4*)agg, n_aggz, n_nodes);

    int nsub    = (n_edges + EPG - 1) / EPG;   // 16-lane subgroups
    int eblocks = (nsub + 15) / 16;            // 16 subgroups per 256-thread block
    edge_kernel<<<eblocks, 256, 0, stream>>>(
        Ak, Bq8, senders, receivers, couplings, W1, agg, n_edges, e_half);

    int n4 = (int)(N32 / 4);
    relu_widen_copy<<<(n4 + 255) / 256, 256, 0, stream>>>(
        (const uint2*)agg, (float4*)out, n4);
}

// Round 11
// 274.099 us; speedup vs baseline: 2.5006x; 1.0091x over previous
//
#include <hip/hip_runtime.h>
#include <hip/hip_bf16.h>
#include <cstdint>

// AttentionGNNLayer factored form — FINAL (R19 = R8/Round-0 baseline verbatim).
//   per-node A=h@W1a+b1, B=h@W1b, q=h@Wq+bq, k=h@Wk+bk  (W1a=W1 rows 0..31, W1b=rows 32..63)
//   per-edge msg = relu(A[r]+B[s]+c*w1c) * sigmoid(q[s]·k[r]), aggregated by receiver.
//
// Session ledger (why this exact kernel is terminal):
//  - R8 passed twice: 276.9us absmax 1.0 (R0) and 279.4us absmax 1.0 (R13 variant).
//  - fp8 Bq compression (R14): passed ONCE at absmax 1.5, then the BYTE-IDENTICAL
//    kernel failed at 2.0 (R18) -- bf16-atomic accumulation order jitter straddles
//    the 1.82 threshold. fp8 is threshold-marginal, and its 5us edge gain was
//    invisible at bench level (276.6 vs 276.9). Dropped. Receiver-side fp8 provably
//    fails (R15 4.0, R16 2.0: per-receiver systematic error x Sum(sigmoid)~16).
//  - edge kernel is byte-bound at ~3.65 TB/s for random 64/128B gathers +
//    line-granular atomic RMW (R13: per-lane skip left WRITE flat at 161.85MB =
//    surviving_edges x 64B; occupancy 50->78% no dur change R13/R14).
//  - atomic traffic (324MB RMW) irreducible without receiver sorting: bucketing
//    tried 3x (R9 slow-pass, R10/R11 opaque fails), economics negative.
//  - dispatch fusion: cooperative launch = 4x kernel collapse (R12); manual-barrier
//    persistent kernel = container failure (R17). The ~120us total-vs-kernel gap is
//    the harness's own re-poison/restore dispatches; not removable from here.
// Edge transaction budget: 2x128B gathers + 1x64B pk-bf16 atomic = ~5 line-trans/edge.

#define EPG 8   // edges per 16-lane subgroup (edge kernel)

typedef int   vint4   __attribute__((ext_vector_type(4)));
typedef float vfloat4 __attribute__((ext_vector_type(4)));

__device__ __forceinline__ float bf16lo(uint32_t u) {
    uint32_t b = (u & 0xFFFFu) << 16;
    float f; __builtin_memcpy(&f, &b, 4); return f;
}
__device__ __forceinline__ float bf16hi(uint32_t u) {
    uint32_t b = u & 0xFFFF0000u;
    float f; __builtin_memcpy(&f, &b, 4); return f;
}
__device__ __forceinline__ uint32_t pack_bf16(float lo, float hi) {
    __hip_bfloat16 l = __float2bfloat16(lo);
    __hip_bfloat16 h = __float2bfloat16(hi);
    uint16_t lb, hb;
    __builtin_memcpy(&lb, &l, 2);
    __builtin_memcpy(&hb, &h, 2);
    return (uint32_t)lb | ((uint32_t)hb << 16);
}

__device__ __forceinline__ void atomic_pk_add_bf16(uint32_t* addr, uint32_t val) {
    // packed 2x bf16 atomic add; fire-and-forget (no return)
    asm volatile("global_atomic_pk_add_bf16 %0, %1, off" :: "v"(addr), "v"(val) : "memory");
}

// ---- node precompute: weight columns in registers, wave-specialized; also zeros agg ----
// Block = 256 threads = 4 waves. Waves 0,2: (A,k)->Ak. Waves 1,3: (B,q)->Bq.

__global__ __launch_bounds__(256) void node_precompute(
    const float* __restrict__ h, const float* __restrict__ W1,
    const float* __restrict__ b1, const float* __restrict__ Wq,
    const float* __restrict__ bq, const float* __restrict__ Wk,
    const float* __restrict__ bk,
    uint32_t* __restrict__ Ak, uint32_t* __restrict__ Bq,
    uint4* __restrict__ aggz, int n_aggz, int n_nodes)
{
    // zero the bf16 accumulator (folded dispatch)
    for (int i = blockIdx.x * 256 + threadIdx.x; i < n_aggz; i += gridDim.x * 256)
        aggz[i] = make_uint4(0u, 0u, 0u, 0u);

    __shared__ float sW[4][32 * 33];   // +1 pad: conflict-free column reads
    int tid = threadIdx.x;
    for (int i = tid; i < 1024; i += 256) {
        int j = i >> 5, t = i & 31;
        sW[0][j * 33 + t] = W1[i];          // W1a (receiver part)
        sW[1][j * 33 + t] = W1[1024 + i];   // W1b (sender part)
        sW[2][j * 33 + t] = Wq[i];
        sW[3][j * 33 + t] = Wk[i];
    }
    __syncthreads();

    int t    = tid & 31;          // channel
    int wave = tid >> 6;          // 0..3
    int half = wave & 1;          // 0: (A,k)->Ak, 1: (B,q)->Bq
    int sub  = (tid >> 5) & 1;    // group within wave
    int nib  = (wave >> 1) * 2 + sub;   // node slot in block: 0..3

    int ma = half ? 1 : 0;        // W1b : W1a
    int mb = half ? 2 : 3;        // Wq  : Wk
    float wa[32], wb[32];
    #pragma unroll
    for (int j = 0; j < 32; ++j) {
        wa[j] = sW[ma][j * 33 + t];
        wb[j] = sW[mb][j * 33 + t];
    }
    float ba = half ? 0.f    : b1[t];
    float bb = half ? bq[t]  : bk[t];
    uint32_t* dst = half ? Bq : Ak;

    for (int n = blockIdx.x * 4 + nib; n < n_nodes; n += gridDim.x * 4) {
        float hv = h[n * 32 + t];
        float aa = ba, ab = bb;
        #pragma unroll
        for (int j = 0; j < 32; ++j) {
            float hj = __shfl(hv, j, 32);
            aa = fmaf(hj, wa[j], aa);
            ab = fmaf(hj, wb[j], ab);
        }
        dst[n * 32 + t] = pack_bf16(aa, ab);
    }
}

// ---- edge kernel: 16 lanes = one edge (2 channels/lane); 8 edges batched ----

__global__ __launch_bounds__(256) void edge_kernel(
    const uint32_t* __restrict__ Ak, const uint32_t* __restrict__ Bq,
    const int* __restrict__ senders, const int* __restrict__ receivers,
    const float* __restrict__ couplings, const float* __restrict__ W1,
    uint32_t* __restrict__ agg, int n_edges, int e_half)
{
    int lane = threadIdx.x & 15;                       // lane within edge
    int sg   = (blockIdx.x * 256 + threadIdx.x) >> 4;  // global 16-lane subgroup id
    float w0 = W1[64 * 32 + 2 * lane];                 // coupling row (L1-resident)
    float w1 = W1[64 * 32 + 2 * lane + 1];
    int e0 = sg * EPG;
    if (e0 >= n_edges) return;

    int r[EPG], s[EPG];
    float c[EPG];

    bool straddle = (e0 < e_half) && (e0 + EPG > e_half);
    if (e0 + EPG <= n_edges && !straddle) {
        // nontemporal: streamed once, keep out of caches so gathers stay resident
        #pragma unroll
        for (int v = 0; v < EPG / 4; ++v) {
            vint4 rv = __builtin_nontemporal_load((const vint4*)(receivers + e0) + v);
            vint4 sv = __builtin_nontemporal_load((const vint4*)(senders   + e0) + v);
            r[4*v+0]=rv.x; r[4*v+1]=rv.y; r[4*v+2]=rv.z; r[4*v+3]=rv.w;
            s[4*v+0]=sv.x; s[4*v+1]=sv.y; s[4*v+2]=sv.z; s[4*v+3]=sv.w;
        }
        int cb = (e0 < e_half) ? e0 : e0 - e_half;
        #pragma unroll
        for (int v = 0; v < EPG / 4; ++v) {
            vfloat4 cv = __builtin_nontemporal_load((const vfloat4*)(couplings + cb) + v);
            c[4*v+0]=cv.x; c[4*v+1]=cv.y; c[4*v+2]=cv.z; c[4*v+3]=cv.w;
        }
    } else {
        #pragma unroll
        for (int j = 0; j < EPG; ++j) {
            int e = e0 + j;
            if (e < n_edges) {
                r[j] = receivers[e];
                s[j] = senders[e];
                c[j] = couplings[e < e_half ? e : e - e_half];
            } else { r[j] = 0; s[j] = 0; c[j] = 0.f; }
        }
    }

    // interleaved gather issue: compute on edge j can start after 2(j+1) retirements
    uint2 ak[EPG], bq[EPG];
    #pragma unroll
    for (int j = 0; j < EPG; ++j) {
        ak[j] = ((const uint2*)Ak)[(size_t)r[j] * 16 + lane];
        bq[j] = ((const uint2*)Bq)[(size_t)s[j] * 16 + lane];
    }

    #pragma unroll
    for (int j = 0; j < EPG; ++j) {
        float A0 = bf16lo(ak[j].x), k0 = bf16hi(ak[j].x);
        float A1 = bf16lo(ak[j].y), k1 = bf16hi(ak[j].y);
        float B0 = bf16lo(bq[j].x), q0 = bf16hi(bq[j].x);
        float B1 = bf16lo(bq[j].y), q1 = bf16hi(bq[j].y);

        float m0 = fmaxf(fmaf(c[j], w0, A0 + B0), 0.f);
        float m1 = fmaxf(fmaf(c[j], w1, A1 + B1), 0.f);

        float d = fmaf(q0, k0, q1 * k1);
        d += __shfl_xor(d, 1, 64);
        d += __shfl_xor(d, 2, 64);
        d += __shfl_xor(d, 4, 64);
        d += __shfl_xor(d, 8, 64);                     // full 16-lane dot

        // sigmoid(d) < 6.7e-3 -> contribution < ~0.013/edge: skip the atomic
        if (d > -5.f && e0 + j < n_edges) {
            float sig = __fdividef(1.f, 1.f + __expf(-d));
            uint32_t val = pack_bf16(m0 * sig, m1 * sig);
            // ONE 64-B-span packed-bf16 atomic per edge
            atomic_pk_add_bf16(agg + (size_t)r[j] * 16 + lane, val);
        }
    }
}

__global__ __launch_bounds__(256) void relu_widen_copy(
    const uint2* __restrict__ agg, float4* __restrict__ out, int n4)
{
    int i = blockIdx.x * 256 + threadIdx.x;
    if (i < n4) {
        uint2 v = agg[i];
        float4 o;
        o.x = fmaxf(bf16lo(v.x), 0.f);
        o.y = fmaxf(bf16hi(v.x), 0.f);
        o.z = fmaxf(bf16lo(v.y), 0.f);
        o.w = fmaxf(bf16hi(v.y), 0.f);
        out[i] = o;
    }
}

extern "C" void kernel_launch(void* const* d_in, const int* in_sizes, int n_in,
                              void* d_out, int out_size, void* d_ws, size_t ws_size,
                              hipStream_t stream)
{
    const float* h         = (const float*)d_in[0];
    const float* couplings = (const float*)d_in[1];
    const float* W1        = (const float*)d_in[2];
    const float* b1        = (const float*)d_in[3];
    const float* Wq        = (const float*)d_in[4];
    const float* bq        = (const float*)d_in[5];
    const float* Wk        = (const float*)d_in[6];
    const float* bk        = (const float*)d_in[7];
    const int*   senders   = (const int*)d_in[8];
    const int*   receivers = (const int*)d_in[9];
    float* out = (float*)d_out;

    int n_nodes = in_sizes[0] / 32;
    int e_half  = in_sizes[1];
    int n_edges = in_sizes[8];

    size_t N32 = (size_t)n_nodes * 32;

    // ws layout: Ak (u32 x N32) | Bq (u32 x N32) | agg (bf16 x N32 = N32/2 u32)
    uint32_t* Ak  = (uint32_t*)d_ws;
    uint32_t* Bq  = Ak + N32;
    uint32_t* agg = Bq + N32;
    int n_aggz = (int)(N32 / 8);   // uint4 count covering N32*2 bytes

    node_precompute<<<2048, 256, 0, stream>>>(
        h, W1, b1, Wq, bq, Wk, bk, Ak, Bq, (uint4*)agg, n_aggz, n_nodes);

    int nsub    = (n_edges + EPG - 1) / EPG;   // 16-lane subgroups
    int eblocks = (nsub + 15) / 16;            // 16 subgroups per 256-thread block
    edge_kernel<<<eblocks, 256, 0, stream>>>(
        Ak, Bq, senders, receivers, couplings, W1, agg, n_edges, e_half);

    int n4 = (int)(N32 / 4);
    relu_widen_copy<<<(n4 + 255) / 256, 256, 0, stream>>>(
        (const uint2*)agg, (float4*)out, n4);
}